// Round 6
// baseline (265.470 us; speedup 1.0000x reference)
//
#include <hip/hip_runtime.h>

typedef short bf16x8 __attribute__((ext_vector_type(8)));
typedef float f32x4 __attribute__((ext_vector_type(4)));

__device__ inline float bf2f(ushort u) {
    unsigned v = ((unsigned)u) << 16;
    return __builtin_bit_cast(float, v);
}
__device__ inline ushort f2bf(float f) {
    unsigned u = __builtin_bit_cast(unsigned, f);
    u += 0x7fffu + ((u >> 16) & 1u);
    return (ushort)(u >> 16);
}
__device__ inline void async_load16(const ushort* g, ushort* l) {
    __builtin_amdgcn_global_load_lds((const __attribute__((address_space(1))) void*)g,
                                     (__attribute__((address_space(3))) void*)l, 16, 0, 0);
}

// Single merged fp32->bf16 cast for all 5 tensors. 8 elems/thread.
__global__ void cast_all(const float* __restrict__ hs, const float* __restrict__ Wq,
                         const float* __restrict__ Wk, const float* __restrict__ Wv,
                         const float* __restrict__ Ws,
                         ushort* __restrict__ dhs, ushort* __restrict__ dWq,
                         ushort* __restrict__ dWk, ushort* __restrict__ dWv,
                         ushort* __restrict__ dWs)
{
    int bid = blockIdx.x;
    const float* src; ushort* dst; int off;
    if (bid < 2048)      { src = hs; dst = dhs; off = bid; }
    else if (bid < 2560) { src = Wq; dst = dWq; off = bid - 2048; }
    else if (bid < 3072) { src = Wk; dst = dWk; off = bid - 2560; }
    else if (bid < 3584) { src = Wv; dst = dWv; off = bid - 3072; }
    else                 { src = Ws; dst = dWs; off = bid - 3584; }
    int i = (off * 256 + threadIdx.x) * 8;
    float4 a = *(const float4*)(src + i);
    float4 b = *(const float4*)(src + i + 4);
    union { ushort u[8]; float4 v; } o;
    o.u[0] = f2bf(a.x); o.u[1] = f2bf(a.y); o.u[2] = f2bf(a.z); o.u[3] = f2bf(a.w);
    o.u[4] = f2bf(b.x); o.u[5] = f2bf(b.y); o.u[6] = f2bf(b.z); o.u[7] = f2bf(b.w);
    *(float4*)(dst + i) = o.v;
}

// Fused QKVS projection (unchanged). X:[4096,1024] bf16, W*:[N,1024] bf16, bias fp32.
// xb 0-7 -> Q (scaled 0.125*log2e), 8-15 -> K, 16-23 -> V (transposed to VtG[bh][d][s]),
// 24-25 -> S (sigmoid -> fp32 sb). LDS XOR chunk swizzle: chunk c of row r at slot c^(r&7).
__launch_bounds__(256, 4)
__global__ void fused_qkvs(const ushort* __restrict__ X,
                           const ushort* __restrict__ Wq, const ushort* __restrict__ Wk,
                           const ushort* __restrict__ Wv, const ushort* __restrict__ Ws,
                           const float* __restrict__ bq, const float* __restrict__ bk,
                           const float* __restrict__ bv, const float* __restrict__ bs,
                           ushort* __restrict__ Qb, ushort* __restrict__ Kb,
                           ushort* __restrict__ VtG, float* __restrict__ sb)
{
    __shared__ __align__(16) ushort Sm[128 * 136];
    ushort* As = Sm;
    ushort* Bs = Sm + 128 * 64;

    const int tid = threadIdx.x, w = tid >> 6, lane = tid & 63;
    const int l15 = lane & 15, quad = lane >> 4;
    const int lrow = lane >> 3;
    const int gchunk = ((lane & 7) ^ lrow) * 8;

    const int wid = blockIdx.x;
    const int r8 = wid & 7, jj = wid >> 3;
    const int by = (jj & 3) * 8 + r8;
    const int xb = jj >> 2;
    const int m0 = by * 128;

    const ushort* W; const float* bias; int n0, mode;
    if (xb < 8)       { W = Wq; bias = bq; n0 = xb * 128;        mode = 1; }
    else if (xb < 16) { W = Wk; bias = bk; n0 = (xb - 8) * 128;  mode = 0; }
    else if (xb < 24) { W = Wv; bias = bv; n0 = (xb - 16) * 128; mode = 2; }
    else              { W = Ws; bias = bs; n0 = (xb - 24) * 128; mode = 3; }

    const int wm = (w >> 1) * 64, wn = (w & 1) * 64;

    f32x4 acc[4][4];
    for (int i = 0; i < 4; i++) for (int j = 0; j < 4; j++) acc[i][j] = (f32x4){0.f, 0.f, 0.f, 0.f};

    for (int k0 = 0; k0 < 1024; k0 += 64) {
        __syncthreads();
        for (int c = 0; c < 4; ++c) {
            int r = w * 32 + c * 8;
            async_load16(&X[(size_t)(m0 + r + lrow) * 1024 + k0 + gchunk], &As[r * 64]);
            async_load16(&W[(size_t)(n0 + r + lrow) * 1024 + k0 + gchunk], &Bs[r * 64]);
        }
        __syncthreads();
        for (int kk = 0; kk < 64; kk += 32) {
            const int csw = quad + (kk >> 3);
            bf16x8 a[4], b[4];
            for (int i = 0; i < 4; i++)
                a[i] = *(const bf16x8*)&As[(wm + i * 16 + l15) * 64 + ((csw ^ (l15 & 7)) * 8)];
            for (int j = 0; j < 4; j++)
                b[j] = *(const bf16x8*)&Bs[(wn + j * 16 + l15) * 64 + ((csw ^ (l15 & 7)) * 8)];
            for (int i = 0; i < 4; i++)
                for (int j = 0; j < 4; j++)
                    acc[i][j] = __builtin_amdgcn_mfma_f32_16x16x32_bf16(a[i], b[j], acc[i][j], 0, 0, 0);
        }
    }

    const float QSCALE = 0.125f * 1.44269504f;

    if (mode == 3) {
        for (int i = 0; i < 4; i++)
            for (int j = 0; j < 4; j++) {
                int gn = n0 + wn + j * 16 + l15;
                float bv_ = bias[gn];
                for (int r = 0; r < 4; r++) {
                    int gm = m0 + wm + i * 16 + quad * 4 + r;
                    float v = acc[i][j][r] + bv_;
                    float sg = __builtin_amdgcn_rcpf(1.0f + __builtin_amdgcn_exp2f(-v * 1.44269504f));
                    sb[(size_t)gm * 256 + gn] = sg * 0.1f + 0.95f;
                }
            }
        return;
    }

    __syncthreads();

    if (mode == 2) {
        for (int i = 0; i < 4; i++)
            for (int j = 0; j < 4; j++) {
                int gnl = wn + j * 16 + l15;
                float bv_ = bias[n0 + gnl];
                ushort4 pk;
                pk.x = f2bf(acc[i][j][0] + bv_);
                pk.y = f2bf(acc[i][j][1] + bv_);
                pk.z = f2bf(acc[i][j][2] + bv_);
                pk.w = f2bf(acc[i][j][3] + bv_);
                *(ushort4*)&Sm[gnl * 136 + wm + i * 16 + quad * 4] = pk;
            }
        __syncthreads();
        const int bb = m0 >> 11, sloc = m0 & 2047;
        for (int it = 0; it < 8; ++it) {
            int d = (tid >> 4) + it * 16;
            int s8 = (tid & 15) * 8;
            float4 v = *(float4*)&Sm[d * 136 + s8];
            int h = (n0 + d) >> 6, dd = d & 63;
            *(float4*)&VtG[(size_t)(bb * 16 + h) * 131072 + (size_t)dd * 2048 + sloc + s8] = v;
        }
    } else {
        for (int i = 0; i < 4; i++)
            for (int j = 0; j < 4; j++) {
                int gnl = wn + j * 16 + l15;
                float bv_ = bias[n0 + gnl];
                for (int r = 0; r < 4; r++) {
                    float v = acc[i][j][r] + bv_;
                    if (mode == 1) v *= QSCALE;
                    Sm[(wm + i * 16 + quad * 4 + r) * 136 + gnl] = f2bf(v);
                }
            }
        __syncthreads();
        ushort* dst = (mode == 1) ? Qb : Kb;
        for (int it = 0; it < 8; ++it) {
            int row = (tid >> 4) + it * 16, c = (tid & 15) * 8;
            *(float4*)&dst[(size_t)(m0 + row) * 1024 + n0 + c] = *(float4*)&Sm[row * 136 + c];
        }
    }
}

// Flash attention v17: v15 (4 waves x 16 q-rows) + V-in-registers at prefetch
// distance 1 (v14's verified ping-pong schedule). vb for tile t+1 issues right
// after the step-t barrier alongside the K global_load_lds prefetch; consumed
// after the NEXT barrier -- the barrier's vmcnt drain (which happens anyway)
// covers its latency, unlike v16's same-step loads which serialized the pipe.
// Per block-step LDS 96KB -> 56KB (V staging + 4x-redundant vb reads gone).
__launch_bounds__(256, 4)
__global__ void attn_kernel(const ushort* __restrict__ Q, const ushort* __restrict__ K,
                            const ushort* __restrict__ Vt, const float* __restrict__ sb,
                            float* __restrict__ out)
{
    __shared__ __align__(16) ushort SmA[2 * 4096];   // 16KB: Ks0|Ks1
    __shared__ __align__(16) ushort Ps[4096];        // 8KB: 4 waves x (16 rows x 64)
    ushort* Ks0 = SmA;
    ushort* Ks1 = SmA + 4096;
    ushort* Qs  = SmA + 4096;    // aliases Ks1: dead until STEP(0)'s prefetch (post-hoist)

    const int tid = threadIdx.x, w = tid >> 6, lane = tid & 63;
    const int l15 = lane & 15, quad = lane >> 4;
    const int lrow = lane >> 3;
    const int gchunk = ((lane & 7) ^ lrow) * 8;

    // XCD swizzle: same bh (same K/V) -> same XCD
    const int wid = blockIdx.x;
    const int r8 = wid & 7, jj = wid >> 3;
    const int bh = (jj & 3) * 8 + r8;    // 0..31
    const int qx = jj >> 2;              // 0..31
    const int b = bh >> 4, h = bh & 15;
    const int q0 = qx * 64;
    const size_t rowbase = (size_t)b * 2048;
    const int cbase = h * 64;

    // global staging bases (per-thread, loop-invariant); each wave stages 16 K rows
    const ushort* kg = K + (rowbase + w * 16 + lrow) * 1024 + cbase + gchunk;
    // V frag base (wave-independent, v14-verified): frag(kk2,nt) at tile kt =
    // vgr + kt*64 + nt*32768 + kk2*32 = VtG[bh][d = nt*16+l15][s = kt*64+(kk2*4+quad)*8]
    const ushort* vgr = Vt + (size_t)bh * 131072 + (size_t)l15 * 2048 + quad * 8;

    // prefetch K tile 0 (LDS) FIRST, then V tile 0 (registers)
    for (int c = 0; c < 2; ++c)
        async_load16(kg + c * 8192, Ks0 + w * 1024 + c * 512);
    bf16x8 vbA[2][4], vbB[2][4];
#pragma unroll
    for (int kk2 = 0; kk2 < 2; kk2++)
#pragma unroll
        for (int nt = 0; nt < 4; nt++)
            vbA[kk2][nt] = *(const bf16x8*)(vgr + nt * 32768 + kk2 * 32);

    // stage Q tile into Qs (pitch 64, XOR chunk swizzle), applying groupwise scale s
    for (int it = 0; it < 2; ++it) {
        int l = tid + it * 256;           // 0..511
        int r = l >> 3, ch = l & 7;       // row 0..63, chunk 0..7
        int c = ch * 8;
        union { float4 f; ushort u[8]; } uu, oo;
        uu.f = *(const float4*)&Q[(rowbase + q0 + r) * 1024 + cbase + c];
        const float* sp = &sb[(rowbase + q0 + r) * 256 + ((cbase + c) >> 2)];
        float s0 = sp[0], s1 = sp[1];
        for (int j = 0; j < 4; j++) oo.u[j] = f2bf(bf2f(uu.u[j]) * s0);
        for (int j = 4; j < 8; j++) oo.u[j] = f2bf(bf2f(uu.u[j]) * s1);
        *(float4*)&Qs[r * 64 + ((ch ^ (r & 7)) * 8)] = oo.f;
    }
    __syncthreads();   // Qs writes visible to all waves

    // hoist loop-invariant Q frags (MFMA B-operand: lane l15 = q-row); wave owns rows w*16..+16
    bf16x8 aq[2];  // [kk2]
    for (int kk2 = 0; kk2 < 2; kk2++)
        aq[kk2] = *(const bf16x8*)&Qs[(w * 16 + l15) * 64
                                      + (((kk2 * 4 + quad) ^ (l15 & 7)) * 8)];
    // (STEP(0)'s barrier drains these ds_reads before Ks1 gets overwritten)

    // precomputed loop-invariant LDS offsets (K frags)
    int kvoff[2][4];
    for (int kk2 = 0; kk2 < 2; kk2++)
        for (int nt = 0; nt < 4; nt++)
            kvoff[kk2][nt] = (nt * 16 + l15) * 64 + (((quad + kk2 * 4) ^ (l15 & 7)) * 8);
    int wroff2[4], rdoff2[2];
    {
        const int base = w * 1024 + l15 * 64;
        for (int kt2 = 0; kt2 < 4; kt2++)
            wroff2[kt2] = base + (quad & 1) * 4 + (((kt2 * 2 + (quad >> 1)) ^ (l15 & 7)) * 8);
        for (int half = 0; half < 2; half++)
            rdoff2[half] = base + (((half * 4 + quad) ^ (l15 & 7)) * 8);
    }

    // all-ones bf16 B-frag: osum = P @ 1 gives per-q-row softmax denominators
    const bf16x8 vones = {0x3F80, 0x3F80, 0x3F80, 0x3F80, 0x3F80, 0x3F80, 0x3F80, 0x3F80};

    f32x4 osum = (f32x4){0.f, 0.f, 0.f, 0.f};
    f32x4 o[4];
    for (int nt = 0; nt < 4; nt++) o[nt] = (f32x4){0.f, 0.f, 0.f, 0.f};
    const f32x4 z4 = (f32x4){0.f, 0.f, 0.f, 0.f};

#define ATTN_STEP(KC, KN, VB_CUR, VB_NXT, KT, PREFETCH)                                                 \
    {                                                                                                   \
        __syncthreads(); /* vmcnt+lgkm drained: K tile KT + VB_CUR resident; KN free */                 \
        if (PREFETCH) {                                                                                 \
            const int nk = (KT) + 1;                                                                    \
            for (int c = 0; c < 2; ++c)                                                                 \
                async_load16(kg + nk * 65536 + c * 8192, KN + w * 1024 + c * 512);                      \
            _Pragma("unroll")                                                                           \
            for (int kk2 = 0; kk2 < 2; kk2++)                                                           \
                _Pragma("unroll")                                                                       \
                for (int nt = 0; nt < 4; nt++)                                                          \
                    VB_NXT[kk2][nt] = *(const bf16x8*)(vgr + nk * 64 + nt * 32768 + kk2 * 32);          \
        }                                                                                               \
        bf16x8 kb[2][4];                                                                                \
        for (int kk2 = 0; kk2 < 2; kk2++)                                                               \
            for (int nt = 0; nt < 4; nt++)                                                              \
                kb[kk2][nt] = *(const bf16x8*)&KC[kvoff[kk2][nt]];                                      \
        /* S^T: A = K frag (m=key), B = Q frag (n=q-row) */                                             \
        f32x4 st[4];                                                                                    \
        for (int kt2 = 0; kt2 < 4; kt2++) {                                                             \
            st[kt2] = __builtin_amdgcn_mfma_f32_16x16x32_bf16(kb[0][kt2], aq[0], z4, 0, 0, 0);          \
            st[kt2] = __builtin_amdgcn_mfma_f32_16x16x32_bf16(kb[1][kt2], aq[1], st[kt2], 0, 0, 0);     \
        }                                                                                               \
        for (int kt2 = 0; kt2 < 4; kt2++) {                                                             \
            float p0 = __builtin_amdgcn_exp2f(st[kt2][0]);                                              \
            float p1 = __builtin_amdgcn_exp2f(st[kt2][1]);                                              \
            float p2 = __builtin_amdgcn_exp2f(st[kt2][2]);                                              \
            float p3 = __builtin_amdgcn_exp2f(st[kt2][3]);                                              \
            unsigned d0 = __builtin_amdgcn_perm(__builtin_bit_cast(unsigned, p1) + 0x8000u,             \
                                                __builtin_bit_cast(unsigned, p0) + 0x8000u,             \
                                                0x07060302u);                                           \
            unsigned d1 = __builtin_amdgcn_perm(__builtin_bit_cast(unsigned, p3) + 0x8000u,             \
                                                __builtin_bit_cast(unsigned, p2) + 0x8000u,             \
                                                0x07060302u);                                           \
            uint2 pk; pk.x = d0; pk.y = d1;                                                             \
            *(uint2*)&Ps[wroff2[kt2]] = pk;                                                             \
        }                                                                                               \
        /* O += P @ V (strip wave-private; in-wave DS ordering covers WAR across steps) */              \
        for (int half = 0; half < 2; half++) {                                                          \
            bf16x8 a_ = *(const bf16x8*)&Ps[rdoff2[half]];                                              \
            osum = __builtin_amdgcn_mfma_f32_16x16x32_bf16(a_, vones, osum, 0, 0, 0);                   \
            for (int nt = 0; nt < 4; nt++)                                                              \
                o[nt] = __builtin_amdgcn_mfma_f32_16x16x32_bf16(a_, VB_CUR[half][nt],                   \
                                                                o[nt], 0, 0, 0);                        \
        }                                                                                               \
    }

    for (int kt = 0; kt < 32; kt += 2) {
        ATTN_STEP(Ks0, Ks1, vbA, vbB, kt, 1);
        ATTN_STEP(Ks1, Ks0, vbB, vbA, kt + 1, (kt + 2 < 32));
    }
#undef ATTN_STEP

    // finalize: osum[r] is the full row sum for q-row quad*4+r (replicated over l15)
    for (int r = 0; r < 4; r++) {
        float iv = __builtin_amdgcn_rcpf(osum[r]);
        int q = q0 + w * 16 + quad * 4 + r;
        size_t base = (rowbase + q) * 1024 + cbase;
        for (int nt = 0; nt < 4; nt++)
            out[base + nt * 16 + l15] = o[nt][r] * iv;
    }
}

extern "C" void kernel_launch(void* const* d_in, const int* in_sizes, int n_in,
                              void* d_out, int out_size, void* d_ws, size_t ws_size,
                              hipStream_t stream) {
    const float* hs = (const float*)d_in[0];
    const float* Wq = (const float*)d_in[1];
    const float* bq = (const float*)d_in[2];
    const float* Wk = (const float*)d_in[3];
    const float* bk = (const float*)d_in[4];
    const float* Wv = (const float*)d_in[5];
    const float* bv = (const float*)d_in[6];
    const float* Ws = (const float*)d_in[7];
    const float* bs = (const float*)d_in[8];
    float* outp = (float*)d_out;

    char* ws = (char*)d_ws;
    ushort* Qb    = (ushort*)(ws);                 //  8 MB
    ushort* Kb    = (ushort*)(ws + 8388608);       //  8 MB
    ushort* VtG   = (ushort*)(ws + 16777216);      //  8 MB (V transposed [bh][d][s])
    float*  sb    = (float* )(ws + 25165824);      //  4 MB
    ushort* hs_bf = (ushort*)(ws + 29360128);      //  8 MB
    ushort* Wq_bf = (ushort*)(ws + 37748736);      //  2 MB
    ushort* Wk_bf = (ushort*)(ws + 39845888);      //  2 MB
    ushort* Wv_bf = (ushort*)(ws + 41943040);      //  2 MB
    ushort* Ws_bf = (ushort*)(ws + 44040192);      // 0.5 MB -> total 44,564,480 B

    cast_all<<<dim3(3712), dim3(256), 0, stream>>>(hs, Wq, Wk, Wv, Ws,
                                                   hs_bf, Wq_bf, Wk_bf, Wv_bf, Ws_bf);
    fused_qkvs<<<dim3(832), dim3(256), 0, stream>>>(hs_bf, Wq_bf, Wk_bf, Wv_bf, Ws_bf,
                                                    bq, bk, bv, bs, Qb, Kb, VtG, sb);
    attn_kernel<<<dim3(1024), dim3(256), 0, stream>>>(Qb, Kb, VtG, sb, outp);
}

// Round 7
// 249.402 us; speedup vs baseline: 1.0644x; 1.0644x over previous
//
#include <hip/hip_runtime.h>

typedef short bf16x8 __attribute__((ext_vector_type(8)));
typedef float f32x4 __attribute__((ext_vector_type(4)));

__device__ inline float bf2f(ushort u) {
    unsigned v = ((unsigned)u) << 16;
    return __builtin_bit_cast(float, v);
}
__device__ inline ushort f2bf(float f) {
    unsigned u = __builtin_bit_cast(unsigned, f);
    u += 0x7fffu + ((u >> 16) & 1u);
    return (ushort)(u >> 16);
}
__device__ inline void async_load16(const ushort* g, ushort* l) {
    __builtin_amdgcn_global_load_lds((const __attribute__((address_space(1))) void*)g,
                                     (__attribute__((address_space(3))) void*)l, 16, 0, 0);
}

// Single merged fp32->bf16 cast for all 5 tensors. 8 elems/thread.
__global__ void cast_all(const float* __restrict__ hs, const float* __restrict__ Wq,
                         const float* __restrict__ Wk, const float* __restrict__ Wv,
                         const float* __restrict__ Ws,
                         ushort* __restrict__ dhs, ushort* __restrict__ dWq,
                         ushort* __restrict__ dWk, ushort* __restrict__ dWv,
                         ushort* __restrict__ dWs)
{
    int bid = blockIdx.x;
    const float* src; ushort* dst; int off;
    if (bid < 2048)      { src = hs; dst = dhs; off = bid; }
    else if (bid < 2560) { src = Wq; dst = dWq; off = bid - 2048; }
    else if (bid < 3072) { src = Wk; dst = dWk; off = bid - 2560; }
    else if (bid < 3584) { src = Wv; dst = dWv; off = bid - 3072; }
    else                 { src = Ws; dst = dWs; off = bid - 3584; }
    int i = (off * 256 + threadIdx.x) * 8;
    float4 a = *(const float4*)(src + i);
    float4 b = *(const float4*)(src + i + 4);
    union { ushort u[8]; float4 v; } o;
    o.u[0] = f2bf(a.x); o.u[1] = f2bf(a.y); o.u[2] = f2bf(a.z); o.u[3] = f2bf(a.w);
    o.u[4] = f2bf(b.x); o.u[5] = f2bf(b.y); o.u[6] = f2bf(b.z); o.u[7] = f2bf(b.w);
    *(float4*)(dst + i) = o.v;
}

// Fused QKVS projection (unchanged). X:[4096,1024] bf16, W*:[N,1024] bf16, bias fp32.
// xb 0-7 -> Q (scaled 0.125*log2e), 8-15 -> K, 16-23 -> V (transposed to VtG[bh][d][s]),
// 24-25 -> S (sigmoid -> fp32 sb). LDS XOR chunk swizzle: chunk c of row r at slot c^(r&7).
__launch_bounds__(256, 4)
__global__ void fused_qkvs(const ushort* __restrict__ X,
                           const ushort* __restrict__ Wq, const ushort* __restrict__ Wk,
                           const ushort* __restrict__ Wv, const ushort* __restrict__ Ws,
                           const float* __restrict__ bq, const float* __restrict__ bk,
                           const float* __restrict__ bv, const float* __restrict__ bs,
                           ushort* __restrict__ Qb, ushort* __restrict__ Kb,
                           ushort* __restrict__ VtG, float* __restrict__ sb)
{
    __shared__ __align__(16) ushort Sm[128 * 136];
    ushort* As = Sm;
    ushort* Bs = Sm + 128 * 64;

    const int tid = threadIdx.x, w = tid >> 6, lane = tid & 63;
    const int l15 = lane & 15, quad = lane >> 4;
    const int lrow = lane >> 3;
    const int gchunk = ((lane & 7) ^ lrow) * 8;

    const int wid = blockIdx.x;
    const int r8 = wid & 7, jj = wid >> 3;
    const int by = (jj & 3) * 8 + r8;
    const int xb = jj >> 2;
    const int m0 = by * 128;

    const ushort* W; const float* bias; int n0, mode;
    if (xb < 8)       { W = Wq; bias = bq; n0 = xb * 128;        mode = 1; }
    else if (xb < 16) { W = Wk; bias = bk; n0 = (xb - 8) * 128;  mode = 0; }
    else if (xb < 24) { W = Wv; bias = bv; n0 = (xb - 16) * 128; mode = 2; }
    else              { W = Ws; bias = bs; n0 = (xb - 24) * 128; mode = 3; }

    const int wm = (w >> 1) * 64, wn = (w & 1) * 64;

    f32x4 acc[4][4];
    for (int i = 0; i < 4; i++) for (int j = 0; j < 4; j++) acc[i][j] = (f32x4){0.f, 0.f, 0.f, 0.f};

    for (int k0 = 0; k0 < 1024; k0 += 64) {
        __syncthreads();
        for (int c = 0; c < 4; ++c) {
            int r = w * 32 + c * 8;
            async_load16(&X[(size_t)(m0 + r + lrow) * 1024 + k0 + gchunk], &As[r * 64]);
            async_load16(&W[(size_t)(n0 + r + lrow) * 1024 + k0 + gchunk], &Bs[r * 64]);
        }
        __syncthreads();
        for (int kk = 0; kk < 64; kk += 32) {
            const int csw = quad + (kk >> 3);
            bf16x8 a[4], b[4];
            for (int i = 0; i < 4; i++)
                a[i] = *(const bf16x8*)&As[(wm + i * 16 + l15) * 64 + ((csw ^ (l15 & 7)) * 8)];
            for (int j = 0; j < 4; j++)
                b[j] = *(const bf16x8*)&Bs[(wn + j * 16 + l15) * 64 + ((csw ^ (l15 & 7)) * 8)];
            for (int i = 0; i < 4; i++)
                for (int j = 0; j < 4; j++)
                    acc[i][j] = __builtin_amdgcn_mfma_f32_16x16x32_bf16(a[i], b[j], acc[i][j], 0, 0, 0);
        }
    }

    const float QSCALE = 0.125f * 1.44269504f;

    if (mode == 3) {
        for (int i = 0; i < 4; i++)
            for (int j = 0; j < 4; j++) {
                int gn = n0 + wn + j * 16 + l15;
                float bv_ = bias[gn];
                for (int r = 0; r < 4; r++) {
                    int gm = m0 + wm + i * 16 + quad * 4 + r;
                    float v = acc[i][j][r] + bv_;
                    float sg = __builtin_amdgcn_rcpf(1.0f + __builtin_amdgcn_exp2f(-v * 1.44269504f));
                    sb[(size_t)gm * 256 + gn] = sg * 0.1f + 0.95f;
                }
            }
        return;
    }

    __syncthreads();

    if (mode == 2) {
        for (int i = 0; i < 4; i++)
            for (int j = 0; j < 4; j++) {
                int gnl = wn + j * 16 + l15;
                float bv_ = bias[n0 + gnl];
                ushort4 pk;
                pk.x = f2bf(acc[i][j][0] + bv_);
                pk.y = f2bf(acc[i][j][1] + bv_);
                pk.z = f2bf(acc[i][j][2] + bv_);
                pk.w = f2bf(acc[i][j][3] + bv_);
                *(ushort4*)&Sm[gnl * 136 + wm + i * 16 + quad * 4] = pk;
            }
        __syncthreads();
        const int bb = m0 >> 11, sloc = m0 & 2047;
        for (int it = 0; it < 8; ++it) {
            int d = (tid >> 4) + it * 16;
            int s8 = (tid & 15) * 8;
            float4 v = *(float4*)&Sm[d * 136 + s8];
            int h = (n0 + d) >> 6, dd = d & 63;
            *(float4*)&VtG[(size_t)(bb * 16 + h) * 131072 + (size_t)dd * 2048 + sloc + s8] = v;
        }
    } else {
        for (int i = 0; i < 4; i++)
            for (int j = 0; j < 4; j++) {
                int gnl = wn + j * 16 + l15;
                float bv_ = bias[n0 + gnl];
                for (int r = 0; r < 4; r++) {
                    float v = acc[i][j][r] + bv_;
                    if (mode == 1) v *= QSCALE;
                    Sm[(wm + i * 16 + quad * 4 + r) * 136 + gnl] = f2bf(v);
                }
            }
        __syncthreads();
        ushort* dst = (mode == 1) ? Qb : Kb;
        for (int it = 0; it < 8; ++it) {
            int row = (tid >> 4) + it * 16, c = (tid & 15) * 8;
            *(float4*)&dst[(size_t)(m0 + row) * 1024 + n0 + c] = *(float4*)&Sm[row * 136 + c];
        }
    }
}

// Flash attention v18: v15 (4 waves x 16 q-rows, best known: 63.0us) + single-buffered
// V-in-registers with the two prior failure mechanisms fixed:
//  - vb loads issue FIRST after the barrier (oldest in vmcnt queue) -> the compiler's
//    wait before PV is a counted vmcnt that leaves the K global_load_lds prefetch in
//    flight (v16 issued vb after K -> forced vmcnt(0) serial drain);
//  - sched_barrier(0) right after the loads stops the compiler sinking them to the
//    use site (v16's 48-VGPR tell);
//  - single 32-VGPR buffer, not v17's 64-VGPR ping-pong that spilled under the
//    launch_bounds(256,4) 128-VGPR cap (v17 WRITE_SIZE 38MB = scratch).
// Per block-step LDS 96KB -> 56KB; vb L2 traffic ~24% of L2 BW (4x wave redundancy
// served by L1 since vgr is wave-independent).
__launch_bounds__(256, 4)
__global__ void attn_kernel(const ushort* __restrict__ Q, const ushort* __restrict__ K,
                            const ushort* __restrict__ Vt, const float* __restrict__ sb,
                            float* __restrict__ out)
{
    __shared__ __align__(16) ushort SmA[2 * 4096];   // 16KB: Ks0|Ks1
    __shared__ __align__(16) ushort Ps[4096];        // 8KB: 4 waves x (16 rows x 64)
    ushort* Ks0 = SmA;
    ushort* Ks1 = SmA + 4096;
    ushort* Qs  = SmA + 4096;    // aliases Ks1: dead until STEP(0)'s prefetch (post-hoist)

    const int tid = threadIdx.x, w = tid >> 6, lane = tid & 63;
    const int l15 = lane & 15, quad = lane >> 4;
    const int lrow = lane >> 3;
    const int gchunk = ((lane & 7) ^ lrow) * 8;

    // XCD swizzle: same bh (same K/V) -> same XCD
    const int wid = blockIdx.x;
    const int r8 = wid & 7, jj = wid >> 3;
    const int bh = (jj & 3) * 8 + r8;    // 0..31
    const int qx = jj >> 2;              // 0..31
    const int b = bh >> 4, h = bh & 15;
    const int q0 = qx * 64;
    const size_t rowbase = (size_t)b * 2048;
    const int cbase = h * 64;

    // global staging bases (per-thread, loop-invariant); each wave stages 16 K rows
    const ushort* kg = K + (rowbase + w * 16 + lrow) * 1024 + cbase + gchunk;
    // V frag base (wave-independent, v14-verified): frag(kk2,nt) at tile kt =
    // vgr + kt*64 + nt*32768 + kk2*32 = VtG[bh][d = nt*16+l15][s = kt*64+(kk2*4+quad)*8]
    const ushort* vgr = Vt + (size_t)bh * 131072 + (size_t)l15 * 2048 + quad * 8;

    // prefetch K tile 0 FIRST (Ks0 disjoint from Qs alias)
    for (int c = 0; c < 2; ++c)
        async_load16(kg + c * 8192, Ks0 + w * 1024 + c * 512);

    // stage Q tile into Qs (pitch 64, XOR chunk swizzle), applying groupwise scale s
    for (int it = 0; it < 2; ++it) {
        int l = tid + it * 256;           // 0..511
        int r = l >> 3, ch = l & 7;       // row 0..63, chunk 0..7
        int c = ch * 8;
        union { float4 f; ushort u[8]; } uu, oo;
        uu.f = *(const float4*)&Q[(rowbase + q0 + r) * 1024 + cbase + c];
        const float* sp = &sb[(rowbase + q0 + r) * 256 + ((cbase + c) >> 2)];
        float s0 = sp[0], s1 = sp[1];
        for (int j = 0; j < 4; j++) oo.u[j] = f2bf(bf2f(uu.u[j]) * s0);
        for (int j = 4; j < 8; j++) oo.u[j] = f2bf(bf2f(uu.u[j]) * s1);
        *(float4*)&Qs[r * 64 + ((ch ^ (r & 7)) * 8)] = oo.f;
    }
    __syncthreads();   // Qs writes visible to all waves

    // hoist loop-invariant Q frags (MFMA B-operand: lane l15 = q-row); wave owns rows w*16..+16
    bf16x8 aq[2];  // [kk2]
    for (int kk2 = 0; kk2 < 2; kk2++)
        aq[kk2] = *(const bf16x8*)&Qs[(w * 16 + l15) * 64
                                      + (((kk2 * 4 + quad) ^ (l15 & 7)) * 8)];
    // (STEP(0)'s barrier drains these ds_reads before Ks1 gets overwritten)

    // precomputed loop-invariant LDS offsets (K frags)
    int kvoff[2][4];
    for (int kk2 = 0; kk2 < 2; kk2++)
        for (int nt = 0; nt < 4; nt++)
            kvoff[kk2][nt] = (nt * 16 + l15) * 64 + (((quad + kk2 * 4) ^ (l15 & 7)) * 8);
    int wroff2[4], rdoff2[2];
    {
        const int base = w * 1024 + l15 * 64;
        for (int kt2 = 0; kt2 < 4; kt2++)
            wroff2[kt2] = base + (quad & 1) * 4 + (((kt2 * 2 + (quad >> 1)) ^ (l15 & 7)) * 8);
        for (int half = 0; half < 2; half++)
            rdoff2[half] = base + (((half * 4 + quad) ^ (l15 & 7)) * 8);
    }

    // all-ones bf16 B-frag: osum = P @ 1 gives per-q-row softmax denominators
    const bf16x8 vones = {0x3F80, 0x3F80, 0x3F80, 0x3F80, 0x3F80, 0x3F80, 0x3F80, 0x3F80};

    f32x4 osum = (f32x4){0.f, 0.f, 0.f, 0.f};
    f32x4 o[4];
    for (int nt = 0; nt < 4; nt++) o[nt] = (f32x4){0.f, 0.f, 0.f, 0.f};
    const f32x4 z4 = (f32x4){0.f, 0.f, 0.f, 0.f};

#define ATTN_STEP(KC, KN, KT, PREFETCH)                                                                 \
    {                                                                                                   \
        __syncthreads(); /* K tile KT resident; buffer KN free */                                       \
        /* V frags for THIS tile: issue FIRST (oldest in vmcnt queue), then pin so the                  \
           compiler can't sink them to the PV use site. Wait at PV = counted vmcnt that                 \
           leaves the K prefetch below in flight. */                                                    \
        bf16x8 vb[2][4];                                                                                \
        _Pragma("unroll")                                                                               \
        for (int kk2 = 0; kk2 < 2; kk2++)                                                               \
            _Pragma("unroll")                                                                           \
            for (int nt = 0; nt < 4; nt++)                                                              \
                vb[kk2][nt] = *(const bf16x8*)(vgr + (KT) * 64 + nt * 32768 + kk2 * 32);                \
        __builtin_amdgcn_sched_barrier(0);                                                              \
        if (PREFETCH) {                                                                                 \
            const int nk = (KT) + 1;                                                                    \
            for (int c = 0; c < 2; ++c)                                                                 \
                async_load16(kg + nk * 65536 + c * 8192, KN + w * 1024 + c * 512);                      \
        }                                                                                               \
        bf16x8 kb[2][4];                                                                                \
        for (int kk2 = 0; kk2 < 2; kk2++)                                                               \
            for (int nt = 0; nt < 4; nt++)                                                              \
                kb[kk2][nt] = *(const bf16x8*)&KC[kvoff[kk2][nt]];                                      \
        /* S^T: A = K frag (m=key), B = Q frag (n=q-row) */                                             \
        f32x4 st[4];                                                                                    \
        for (int kt2 = 0; kt2 < 4; kt2++) {                                                             \
            st[kt2] = __builtin_amdgcn_mfma_f32_16x16x32_bf16(kb[0][kt2], aq[0], z4, 0, 0, 0);          \
            st[kt2] = __builtin_amdgcn_mfma_f32_16x16x32_bf16(kb[1][kt2], aq[1], st[kt2], 0, 0, 0);     \
        }                                                                                               \
        for (int kt2 = 0; kt2 < 4; kt2++) {                                                             \
            float p0 = __builtin_amdgcn_exp2f(st[kt2][0]);                                              \
            float p1 = __builtin_amdgcn_exp2f(st[kt2][1]);                                              \
            float p2 = __builtin_amdgcn_exp2f(st[kt2][2]);                                              \
            float p3 = __builtin_amdgcn_exp2f(st[kt2][3]);                                              \
            unsigned d0 = __builtin_amdgcn_perm(__builtin_bit_cast(unsigned, p1) + 0x8000u,             \
                                                __builtin_bit_cast(unsigned, p0) + 0x8000u,             \
                                                0x07060302u);                                           \
            unsigned d1 = __builtin_amdgcn_perm(__builtin_bit_cast(unsigned, p3) + 0x8000u,             \
                                                __builtin_bit_cast(unsigned, p2) + 0x8000u,             \
                                                0x07060302u);                                           \
            uint2 pk; pk.x = d0; pk.y = d1;                                                             \
            *(uint2*)&Ps[wroff2[kt2]] = pk;                                                             \
        }                                                                                               \
        /* O += P @ V (strip wave-private; in-wave DS ordering covers WAR across steps) */              \
        for (int half = 0; half < 2; half++) {                                                          \
            bf16x8 a_ = *(const bf16x8*)&Ps[rdoff2[half]];                                              \
            osum = __builtin_amdgcn_mfma_f32_16x16x32_bf16(a_, vones, osum, 0, 0, 0);                   \
            for (int nt = 0; nt < 4; nt++)                                                              \
                o[nt] = __builtin_amdgcn_mfma_f32_16x16x32_bf16(a_, vb[half][nt],                       \
                                                                o[nt], 0, 0, 0);                        \
        }                                                                                               \
    }

    for (int kt = 0; kt < 32; kt += 2) {
        ATTN_STEP(Ks0, Ks1, kt, 1);
        ATTN_STEP(Ks1, Ks0, kt + 1, (kt + 2 < 32));
    }
#undef ATTN_STEP

    // finalize: osum[r] is the full row sum for q-row quad*4+r (replicated over l15)
    for (int r = 0; r < 4; r++) {
        float iv = __builtin_amdgcn_rcpf(osum[r]);
        int q = q0 + w * 16 + quad * 4 + r;
        size_t base = (rowbase + q) * 1024 + cbase;
        for (int nt = 0; nt < 4; nt++)
            out[base + nt * 16 + l15] = o[nt][r] * iv;
    }
}

extern "C" void kernel_launch(void* const* d_in, const int* in_sizes, int n_in,
                              void* d_out, int out_size, void* d_ws, size_t ws_size,
                              hipStream_t stream) {
    const float* hs = (const float*)d_in[0];
    const float* Wq = (const float*)d_in[1];
    const float* bq = (const float*)d_in[2];
    const float* Wk = (const float*)d_in[3];
    const float* bk = (const float*)d_in[4];
    const float* Wv = (const float*)d_in[5];
    const float* bv = (const float*)d_in[6];
    const float* Ws = (const float*)d_in[7];
    const float* bs = (const float*)d_in[8];
    float* outp = (float*)d_out;

    char* ws = (char*)d_ws;
    ushort* Qb    = (ushort*)(ws);                 //  8 MB
    ushort* Kb    = (ushort*)(ws + 8388608);       //  8 MB
    ushort* VtG   = (ushort*)(ws + 16777216);      //  8 MB (V transposed [bh][d][s])
    float*  sb    = (float* )(ws + 25165824);      //  4 MB
    ushort* hs_bf = (ushort*)(ws + 29360128);      //  8 MB
    ushort* Wq_bf = (ushort*)(ws + 37748736);      //  2 MB
    ushort* Wk_bf = (ushort*)(ws + 39845888);      //  2 MB
    ushort* Wv_bf = (ushort*)(ws + 41943040);      //  2 MB
    ushort* Ws_bf = (ushort*)(ws + 44040192);      // 0.5 MB -> total 44,564,480 B

    cast_all<<<dim3(3712), dim3(256), 0, stream>>>(hs, Wq, Wk, Wv, Ws,
                                                   hs_bf, Wq_bf, Wk_bf, Wv_bf, Ws_bf);
    fused_qkvs<<<dim3(832), dim3(256), 0, stream>>>(hs_bf, Wq_bf, Wk_bf, Wv_bf, Ws_bf,
                                                    bq, bk, bv, bs, Qb, Kb, VtG, sb);
    attn_kernel<<<dim3(1024), dim3(256), 0, stream>>>(Qb, Kb, VtG, sb, outp);
}

// Round 9
// 177.277 us; speedup vs baseline: 1.4975x; 1.4068x over previous
//
#include <hip/hip_runtime.h>

typedef short bf16x8 __attribute__((ext_vector_type(8)));
typedef short bf16x4 __attribute__((ext_vector_type(4)));
typedef float f32x4 __attribute__((ext_vector_type(4)));

__device__ inline float bf2f(ushort u) {
    unsigned v = ((unsigned)u) << 16;
    return __builtin_bit_cast(float, v);
}
__device__ inline ushort f2bf(float f) {
    unsigned u = __builtin_bit_cast(unsigned, f);
    u += 0x7fffu + ((u >> 16) & 1u);
    return (ushort)(u >> 16);
}
__device__ inline void async_load16(const ushort* g, ushort* l) {
    __builtin_amdgcn_global_load_lds((const __attribute__((address_space(1))) void*)g,
                                     (__attribute__((address_space(3))) void*)l, 16, 0, 0);
}
// K=16 bf16 MFMA: A[m=l15][k=quad*4+j] == our P C-layout -> PV needs NO transpose.
__device__ inline f32x4 mfma16(bf16x4 a, bf16x4 b, f32x4 c) {
#if __has_builtin(__builtin_amdgcn_mfma_f32_16x16x16_bf16)
    return __builtin_amdgcn_mfma_f32_16x16x16_bf16(a, b, c, 0, 0, 0);
#else
    return __builtin_amdgcn_mfma_f32_16x16x16bf16_1k(a, b, c, 0, 0, 0);
#endif
}

// Single merged fp32->bf16 cast for all 5 tensors. 8 elems/thread.
__global__ void cast_all(const float* __restrict__ hs, const float* __restrict__ Wq,
                         const float* __restrict__ Wk, const float* __restrict__ Wv,
                         const float* __restrict__ Ws,
                         ushort* __restrict__ dhs, ushort* __restrict__ dWq,
                         ushort* __restrict__ dWk, ushort* __restrict__ dWv,
                         ushort* __restrict__ dWs)
{
    int bid = blockIdx.x;
    const float* src; ushort* dst; int off;
    if (bid < 2048)      { src = hs; dst = dhs; off = bid; }
    else if (bid < 2560) { src = Wq; dst = dWq; off = bid - 2048; }
    else if (bid < 3072) { src = Wk; dst = dWk; off = bid - 2560; }
    else if (bid < 3584) { src = Wv; dst = dWv; off = bid - 3072; }
    else                 { src = Ws; dst = dWs; off = bid - 3584; }
    int i = (off * 256 + threadIdx.x) * 8;
    float4 a = *(const float4*)(src + i);
    float4 b = *(const float4*)(src + i + 4);
    union { ushort u[8]; float4 v; } o;
    o.u[0] = f2bf(a.x); o.u[1] = f2bf(a.y); o.u[2] = f2bf(a.z); o.u[3] = f2bf(a.w);
    o.u[4] = f2bf(b.x); o.u[5] = f2bf(b.y); o.u[6] = f2bf(b.z); o.u[7] = f2bf(b.w);
    *(float4*)(dst + i) = o.v;
}

// Fused QKVS projection (unchanged). X:[4096,1024] bf16, W*:[N,1024] bf16, bias fp32.
// xb 0-7 -> Q (scaled 0.125*log2e), 8-15 -> K, 16-23 -> V (transposed to VtG[bh][d][s]),
// 24-25 -> S (sigmoid -> fp32 sb). LDS XOR chunk swizzle: chunk c of row r at slot c^(r&7).
__launch_bounds__(256, 4)
__global__ void fused_qkvs(const ushort* __restrict__ X,
                           const ushort* __restrict__ Wq, const ushort* __restrict__ Wk,
                           const ushort* __restrict__ Wv, const ushort* __restrict__ Ws,
                           const float* __restrict__ bq, const float* __restrict__ bk,
                           const float* __restrict__ bv, const float* __restrict__ bs,
                           ushort* __restrict__ Qb, ushort* __restrict__ Kb,
                           ushort* __restrict__ VtG, float* __restrict__ sb)
{
    __shared__ __align__(16) ushort Sm[128 * 136];
    ushort* As = Sm;
    ushort* Bs = Sm + 128 * 64;

    const int tid = threadIdx.x, w = tid >> 6, lane = tid & 63;
    const int l15 = lane & 15, quad = lane >> 4;
    const int lrow = lane >> 3;
    const int gchunk = ((lane & 7) ^ lrow) * 8;

    const int wid = blockIdx.x;
    const int r8 = wid & 7, jj = wid >> 3;
    const int by = (jj & 3) * 8 + r8;
    const int xb = jj >> 2;
    const int m0 = by * 128;

    const ushort* W; const float* bias; int n0, mode;
    if (xb < 8)       { W = Wq; bias = bq; n0 = xb * 128;        mode = 1; }
    else if (xb < 16) { W = Wk; bias = bk; n0 = (xb - 8) * 128;  mode = 0; }
    else if (xb < 24) { W = Wv; bias = bv; n0 = (xb - 16) * 128; mode = 2; }
    else              { W = Ws; bias = bs; n0 = (xb - 24) * 128; mode = 3; }

    const int wm = (w >> 1) * 64, wn = (w & 1) * 64;

    f32x4 acc[4][4];
    for (int i = 0; i < 4; i++) for (int j = 0; j < 4; j++) acc[i][j] = (f32x4){0.f, 0.f, 0.f, 0.f};

    for (int k0 = 0; k0 < 1024; k0 += 64) {
        __syncthreads();
        for (int c = 0; c < 4; ++c) {
            int r = w * 32 + c * 8;
            async_load16(&X[(size_t)(m0 + r + lrow) * 1024 + k0 + gchunk], &As[r * 64]);
            async_load16(&W[(size_t)(n0 + r + lrow) * 1024 + k0 + gchunk], &Bs[r * 64]);
        }
        __syncthreads();
        for (int kk = 0; kk < 64; kk += 32) {
            const int csw = quad + (kk >> 3);
            bf16x8 a[4], b[4];
            for (int i = 0; i < 4; i++)
                a[i] = *(const bf16x8*)&As[(wm + i * 16 + l15) * 64 + ((csw ^ (l15 & 7)) * 8)];
            for (int j = 0; j < 4; j++)
                b[j] = *(const bf16x8*)&Bs[(wn + j * 16 + l15) * 64 + ((csw ^ (l15 & 7)) * 8)];
            for (int i = 0; i < 4; i++)
                for (int j = 0; j < 4; j++)
                    acc[i][j] = __builtin_amdgcn_mfma_f32_16x16x32_bf16(a[i], b[j], acc[i][j], 0, 0, 0);
        }
    }

    const float QSCALE = 0.125f * 1.44269504f;

    if (mode == 3) {
        for (int i = 0; i < 4; i++)
            for (int j = 0; j < 4; j++) {
                int gn = n0 + wn + j * 16 + l15;
                float bv_ = bias[gn];
                for (int r = 0; r < 4; r++) {
                    int gm = m0 + wm + i * 16 + quad * 4 + r;
                    float v = acc[i][j][r] + bv_;
                    float sg = __builtin_amdgcn_rcpf(1.0f + __builtin_amdgcn_exp2f(-v * 1.44269504f));
                    sb[(size_t)gm * 256 + gn] = sg * 0.1f + 0.95f;
                }
            }
        return;
    }

    __syncthreads();

    if (mode == 2) {
        for (int i = 0; i < 4; i++)
            for (int j = 0; j < 4; j++) {
                int gnl = wn + j * 16 + l15;
                float bv_ = bias[n0 + gnl];
                ushort4 pk;
                pk.x = f2bf(acc[i][j][0] + bv_);
                pk.y = f2bf(acc[i][j][1] + bv_);
                pk.z = f2bf(acc[i][j][2] + bv_);
                pk.w = f2bf(acc[i][j][3] + bv_);
                *(ushort4*)&Sm[gnl * 136 + wm + i * 16 + quad * 4] = pk;
            }
        __syncthreads();
        const int bb = m0 >> 11, sloc = m0 & 2047;
        for (int it = 0; it < 8; ++it) {
            int d = (tid >> 4) + it * 16;
            int s8 = (tid & 15) * 8;
            float4 v = *(float4*)&Sm[d * 136 + s8];
            int h = (n0 + d) >> 6, dd = d & 63;
            *(float4*)&VtG[(size_t)(bb * 16 + h) * 131072 + (size_t)dd * 2048 + sloc + s8] = v;
        }
    } else {
        for (int i = 0; i < 4; i++)
            for (int j = 0; j < 4; j++) {
                int gnl = wn + j * 16 + l15;
                float bv_ = bias[n0 + gnl];
                for (int r = 0; r < 4; r++) {
                    float v = acc[i][j][r] + bv_;
                    if (mode == 1) v *= QSCALE;
                    Sm[(wm + i * 16 + quad * 4 + r) * 136 + gnl] = f2bf(v);
                }
            }
        __syncthreads();
        ushort* dst = (mode == 1) ? Qb : Kb;
        for (int it = 0; it < 8; ++it) {
            int row = (tid >> 4) + it * 16, c = (tid & 15) * 8;
            *(float4*)&dst[(size_t)(m0 + row) * 1024 + n0 + c] = *(float4*)&Sm[row * 136 + c];
        }
    }
}

// Flash attention v20: v15 (4 waves x 16 q-rows, 63.0us verified) with PV switched to
// v_mfma_f32_16x16x16_bf16. Key insight: the K=16 A-operand layout A[m=l15][k=quad*4+j]
// IS the QK^T C-layout we hold (lane(quad,l15) reg r = P[key=kt2*16+quad*4+r][q=l15]) --
// the packed exp dwords {du0,du1} feed PV directly. No Ps LDS round-trip, no permlane,
// no lane-crossing (v19's two correctness failures were both lane-exchange semantics).
// V frags become 16 ds_read_b64 (B-16 layout: V[key=kt2*16+quad*4+j][d=nt*16+l15],
// 4 contiguous ushorts, swizzle-compatible). Per wave-step LDS ~264->~208cy on the
// saturated pipe; write->read latency chain gone; LDS 40KB->32KB.
__launch_bounds__(256, 4)
__global__ void attn_kernel(const ushort* __restrict__ Q, const ushort* __restrict__ K,
                            const ushort* __restrict__ Vt, const float* __restrict__ sb,
                            float* __restrict__ out)
{
    __shared__ __align__(16) ushort SmA[4 * 4096];   // 32KB: Ks0|Ks1|Vs0|Vs1
    ushort* Ks0 = SmA;
    ushort* Ks1 = SmA + 4096;
    ushort* Vs0 = SmA + 8192;
    ushort* Vs1 = SmA + 12288;
    ushort* Qs  = SmA + 4096;    // aliases Ks1: dead until STEP(0)'s prefetch (post-hoist)

    const int tid = threadIdx.x, w = tid >> 6, lane = tid & 63;
    const int l15 = lane & 15, quad = lane >> 4;
    const int lrow = lane >> 3;
    const int gchunk = ((lane & 7) ^ lrow) * 8;

    // XCD swizzle: same bh (same K/V) -> same XCD
    const int wid = blockIdx.x;
    const int r8 = wid & 7, jj = wid >> 3;
    const int bh = (jj & 3) * 8 + r8;    // 0..31
    const int qx = jj >> 2;              // 0..31
    const int b = bh >> 4, h = bh & 15;
    const int q0 = qx * 64;
    const size_t rowbase = (size_t)b * 2048;
    const int cbase = h * 64;

    // global staging bases (per-thread, loop-invariant); each wave stages 16 rows
    const ushort* kg = K + (rowbase + w * 16 + lrow) * 1024 + cbase + gchunk;
    const ushort* vg = Vt + (size_t)bh * 131072 + (size_t)(w * 16 + lrow) * 2048 + gchunk;

    // prefetch K/V tile 0 FIRST (Ks0/Vs0 disjoint from Qs alias)
    for (int c = 0; c < 2; ++c) {
        async_load16(kg + c * 8192,  Ks0 + w * 1024 + c * 512);
        async_load16(vg + c * 16384, Vs0 + w * 1024 + c * 512);
    }

    // stage Q tile into Qs (pitch 64, XOR chunk swizzle), applying groupwise scale s
    for (int it = 0; it < 2; ++it) {
        int l = tid + it * 256;           // 0..511
        int r = l >> 3, ch = l & 7;       // row 0..63, chunk 0..7
        int c = ch * 8;
        union { float4 f; ushort u[8]; } uu, oo;
        uu.f = *(const float4*)&Q[(rowbase + q0 + r) * 1024 + cbase + c];
        const float* sp = &sb[(rowbase + q0 + r) * 256 + ((cbase + c) >> 2)];
        float s0 = sp[0], s1 = sp[1];
        for (int j = 0; j < 4; j++) oo.u[j] = f2bf(bf2f(uu.u[j]) * s0);
        for (int j = 4; j < 8; j++) oo.u[j] = f2bf(bf2f(uu.u[j]) * s1);
        *(float4*)&Qs[r * 64 + ((ch ^ (r & 7)) * 8)] = oo.f;
    }
    __syncthreads();   // Qs writes visible to all waves

    // hoist loop-invariant Q frags (MFMA B-operand: lane l15 = q-row); wave owns rows w*16..+16
    bf16x8 aq[2];  // [kk2]
    for (int kk2 = 0; kk2 < 2; kk2++)
        aq[kk2] = *(const bf16x8*)&Qs[(w * 16 + l15) * 64
                                      + (((kk2 * 4 + quad) ^ (l15 & 7)) * 8)];
    // (STEP(0)'s barrier drains these ds_reads before Ks1 gets overwritten)

    // precomputed loop-invariant LDS offsets
    int kvoff[2][4];   // K frags (A-32 layout: 8 contiguous keys' worth of d per lane)
    for (int kk2 = 0; kk2 < 2; kk2++)
        for (int nt = 0; nt < 4; nt++)
            kvoff[kk2][nt] = (nt * 16 + l15) * 64 + (((quad + kk2 * 4) ^ (l15 & 7)) * 8);
    // V frags (B-16 layout): row d = nt*16+l15, keys kt2*16+quad*4+{0..3}
    // = chunk slot (kt2*2+(quad>>1))^(l15&7), within-chunk offset (quad&1)*4
    int vaddr[4];
    for (int kt2 = 0; kt2 < 4; kt2++)
        vaddr[kt2] = l15 * 64 + (quad & 1) * 4
                   + (((kt2 * 2 + (quad >> 1)) ^ (l15 & 7)) * 8);

    // all-ones bf16 B-frag (K=16): osum = P @ 1 gives per-q-row softmax denominators
    const bf16x4 vones4 = {0x3F80, 0x3F80, 0x3F80, 0x3F80};

    f32x4 osum = (f32x4){0.f, 0.f, 0.f, 0.f};
    f32x4 o[4];
    for (int nt = 0; nt < 4; nt++) o[nt] = (f32x4){0.f, 0.f, 0.f, 0.f};
    const f32x4 z4 = (f32x4){0.f, 0.f, 0.f, 0.f};

#define ATTN_STEP(KC, VC, KN, VN, KT, PREFETCH)                                                         \
    {                                                                                                   \
        __syncthreads(); /* vmcnt+lgkm drained: tile KT resident; buffers KN/VN free */                 \
        if (PREFETCH) {                                                                                 \
            const int nk = (KT) + 1;                                                                    \
            for (int c = 0; c < 2; ++c) {                                                               \
                async_load16(kg + nk * 65536 + c * 8192, KN + w * 1024 + c * 512);                      \
                async_load16(vg + nk * 64 + c * 16384,   VN + w * 1024 + c * 512);                      \
            }                                                                                           \
        }                                                                                               \
        bf16x8 kb[2][4];                                                                                \
        for (int kk2 = 0; kk2 < 2; kk2++)                                                               \
            for (int nt = 0; nt < 4; nt++)                                                              \
                kb[kk2][nt] = *(const bf16x8*)&KC[kvoff[kk2][nt]];                                      \
        bf16x4 vb4[4][4];                                                                               \
        _Pragma("unroll")                                                                               \
        for (int kt2 = 0; kt2 < 4; kt2++)                                                               \
            _Pragma("unroll")                                                                           \
            for (int nt = 0; nt < 4; nt++)                                                              \
                vb4[kt2][nt] = *(const bf16x4*)&VC[vaddr[kt2] + nt * 1024];                             \
        /* S^T: A = K frag (m=key), B = Q frag (n=q-row) */                                             \
        f32x4 st[4];                                                                                    \
        _Pragma("unroll")                                                                               \
        for (int kt2 = 0; kt2 < 4; kt2++) {                                                             \
            st[kt2] = __builtin_amdgcn_mfma_f32_16x16x32_bf16(kb[0][kt2], aq[0], z4, 0, 0, 0);          \
            st[kt2] = __builtin_amdgcn_mfma_f32_16x16x32_bf16(kb[1][kt2], aq[1], st[kt2], 0, 0, 0);     \
        }                                                                                               \
        /* exp + pack: du0=(r0,r1), du1=(r2,r3) -> directly the K=16 A-frag dwords */                   \
        unsigned du0[4], du1[4];                                                                        \
        _Pragma("unroll")                                                                               \
        for (int kt2 = 0; kt2 < 4; kt2++) {                                                             \
            float p0 = __builtin_amdgcn_exp2f(st[kt2][0]);                                              \
            float p1 = __builtin_amdgcn_exp2f(st[kt2][1]);                                              \
            float p2 = __builtin_amdgcn_exp2f(st[kt2][2]);                                              \
            float p3 = __builtin_amdgcn_exp2f(st[kt2][3]);                                              \
            du0[kt2] = __builtin_amdgcn_perm(__builtin_bit_cast(unsigned, p1) + 0x8000u,                \
                                             __builtin_bit_cast(unsigned, p0) + 0x8000u,                \
                                             0x07060302u);                                              \
            du1[kt2] = __builtin_amdgcn_perm(__builtin_bit_cast(unsigned, p3) + 0x8000u,                \
                                             __builtin_bit_cast(unsigned, p2) + 0x8000u,                \
                                             0x07060302u);                                              \
        }                                                                                               \
        /* O += P @ V via K=16 MFMA: A-frag = held C-layout, zero data movement */                      \
        _Pragma("unroll")                                                                               \
        for (int kt2 = 0; kt2 < 4; kt2++) {                                                             \
            union { unsigned u[2]; bf16x4 v; } af;                                                      \
            af.u[0] = du0[kt2]; af.u[1] = du1[kt2];                                                     \
            osum = mfma16(af.v, vones4, osum);                                                          \
            _Pragma("unroll")                                                                           \
            for (int nt = 0; nt < 4; nt++)                                                              \
                o[nt] = mfma16(af.v, vb4[kt2][nt], o[nt]);                                              \
        }                                                                                               \
    }

    for (int kt = 0; kt < 32; kt += 2) {
        ATTN_STEP(Ks0, Vs0, Ks1, Vs1, kt, 1);
        ATTN_STEP(Ks1, Vs1, Ks0, Vs0, kt + 1, (kt + 2 < 32));
    }
#undef ATTN_STEP

    // finalize: osum[r] is the full row sum for q-row quad*4+r (replicated over l15)
    for (int r = 0; r < 4; r++) {
        float iv = __builtin_amdgcn_rcpf(osum[r]);
        int q = q0 + w * 16 + quad * 4 + r;
        size_t base = (rowbase + q) * 1024 + cbase;
        for (int nt = 0; nt < 4; nt++)
            out[base + nt * 16 + l15] = o[nt][r] * iv;
    }
}

extern "C" void kernel_launch(void* const* d_in, const int* in_sizes, int n_in,
                              void* d_out, int out_size, void* d_ws, size_t ws_size,
                              hipStream_t stream) {
    const float* hs = (const float*)d_in[0];
    const float* Wq = (const float*)d_in[1];
    const float* bq = (const float*)d_in[2];
    const float* Wk = (const float*)d_in[3];
    const float* bk = (const float*)d_in[4];
    const float* Wv = (const float*)d_in[5];
    const float* bv = (const float*)d_in[6];
    const float* Ws = (const float*)d_in[7];
    const float* bs = (const float*)d_in[8];
    float* outp = (float*)d_out;

    char* ws = (char*)d_ws;
    ushort* Qb    = (ushort*)(ws);                 //  8 MB
    ushort* Kb    = (ushort*)(ws + 8388608);       //  8 MB
    ushort* VtG   = (ushort*)(ws + 16777216);      //  8 MB (V transposed [bh][d][s])
    float*  sb    = (float* )(ws + 25165824);      //  4 MB
    ushort* hs_bf = (ushort*)(ws + 29360128);      //  8 MB
    ushort* Wq_bf = (ushort*)(ws + 37748736);      //  2 MB
    ushort* Wk_bf = (ushort*)(ws + 39845888);      //  2 MB
    ushort* Wv_bf = (ushort*)(ws + 41943040);      //  2 MB
    ushort* Ws_bf = (ushort*)(ws + 44040192);      // 0.5 MB -> total 44,564,480 B

    cast_all<<<dim3(3712), dim3(256), 0, stream>>>(hs, Wq, Wk, Wv, Ws,
                                                   hs_bf, Wq_bf, Wk_bf, Wv_bf, Ws_bf);
    fused_qkvs<<<dim3(832), dim3(256), 0, stream>>>(hs_bf, Wq_bf, Wk_bf, Wv_bf, Ws_bf,
                                                    bq, bk, bv, bs, Qb, Kb, VtG, sb);
    attn_kernel<<<dim3(1024), dim3(256), 0, stream>>>(Qb, Kb, VtG, sb, outp);
}

// Round 10
// 169.291 us; speedup vs baseline: 1.5681x; 1.0472x over previous
//
#include <hip/hip_runtime.h>

typedef short bf16x8 __attribute__((ext_vector_type(8)));
typedef short bf16x4 __attribute__((ext_vector_type(4)));
typedef float f32x4 __attribute__((ext_vector_type(4)));

__device__ inline float bf2f(ushort u) {
    unsigned v = ((unsigned)u) << 16;
    return __builtin_bit_cast(float, v);
}
__device__ inline ushort f2bf(float f) {
    unsigned u = __builtin_bit_cast(unsigned, f);
    u += 0x7fffu + ((u >> 16) & 1u);
    return (ushort)(u >> 16);
}
__device__ inline void async_load16(const ushort* g, ushort* l) {
    __builtin_amdgcn_global_load_lds((const __attribute__((address_space(1))) void*)g,
                                     (__attribute__((address_space(3))) void*)l, 16, 0, 0);
}
// K=16 bf16 MFMA: A[m=l15][k=quad*4+j] == our P C-layout -> PV needs NO transpose.
__device__ inline f32x4 mfma16(bf16x4 a, bf16x4 b, f32x4 c) {
#if __has_builtin(__builtin_amdgcn_mfma_f32_16x16x16_bf16)
    return __builtin_amdgcn_mfma_f32_16x16x16_bf16(a, b, c, 0, 0, 0);
#else
    return __builtin_amdgcn_mfma_f32_16x16x16bf16_1k(a, b, c, 0, 0, 0);
#endif
}

// Single merged fp32->bf16 cast for all 5 tensors. 8 elems/thread.
__global__ void cast_all(const float* __restrict__ hs, const float* __restrict__ Wq,
                         const float* __restrict__ Wk, const float* __restrict__ Wv,
                         const float* __restrict__ Ws,
                         ushort* __restrict__ dhs, ushort* __restrict__ dWq,
                         ushort* __restrict__ dWk, ushort* __restrict__ dWv,
                         ushort* __restrict__ dWs)
{
    int bid = blockIdx.x;
    const float* src; ushort* dst; int off;
    if (bid < 2048)      { src = hs; dst = dhs; off = bid; }
    else if (bid < 2560) { src = Wq; dst = dWq; off = bid - 2048; }
    else if (bid < 3072) { src = Wk; dst = dWk; off = bid - 2560; }
    else if (bid < 3584) { src = Wv; dst = dWv; off = bid - 3072; }
    else                 { src = Ws; dst = dWs; off = bid - 3584; }
    int i = (off * 256 + threadIdx.x) * 8;
    float4 a = *(const float4*)(src + i);
    float4 b = *(const float4*)(src + i + 4);
    union { ushort u[8]; float4 v; } o;
    o.u[0] = f2bf(a.x); o.u[1] = f2bf(a.y); o.u[2] = f2bf(a.z); o.u[3] = f2bf(a.w);
    o.u[4] = f2bf(b.x); o.u[5] = f2bf(b.y); o.u[6] = f2bf(b.z); o.u[7] = f2bf(b.w);
    *(float4*)(dst + i) = o.v;
}

// Fused QKVS projection (unchanged). X:[4096,1024] bf16, W*:[N,1024] bf16, bias fp32.
// xb 0-7 -> Q (scaled 0.125*log2e), 8-15 -> K, 16-23 -> V (transposed to VtG[bh][d][s]),
// 24-25 -> S (sigmoid -> fp32 sb). LDS XOR chunk swizzle: chunk c of row r at slot c^(r&7).
__launch_bounds__(256, 4)
__global__ void fused_qkvs(const ushort* __restrict__ X,
                           const ushort* __restrict__ Wq, const ushort* __restrict__ Wk,
                           const ushort* __restrict__ Wv, const ushort* __restrict__ Ws,
                           const float* __restrict__ bq, const float* __restrict__ bk,
                           const float* __restrict__ bv, const float* __restrict__ bs,
                           ushort* __restrict__ Qb, ushort* __restrict__ Kb,
                           ushort* __restrict__ VtG, float* __restrict__ sb)
{
    __shared__ __align__(16) ushort Sm[128 * 136];
    ushort* As = Sm;
    ushort* Bs = Sm + 128 * 64;

    const int tid = threadIdx.x, w = tid >> 6, lane = tid & 63;
    const int l15 = lane & 15, quad = lane >> 4;
    const int lrow = lane >> 3;
    const int gchunk = ((lane & 7) ^ lrow) * 8;

    const int wid = blockIdx.x;
    const int r8 = wid & 7, jj = wid >> 3;
    const int by = (jj & 3) * 8 + r8;
    const int xb = jj >> 2;
    const int m0 = by * 128;

    const ushort* W; const float* bias; int n0, mode;
    if (xb < 8)       { W = Wq; bias = bq; n0 = xb * 128;        mode = 1; }
    else if (xb < 16) { W = Wk; bias = bk; n0 = (xb - 8) * 128;  mode = 0; }
    else if (xb < 24) { W = Wv; bias = bv; n0 = (xb - 16) * 128; mode = 2; }
    else              { W = Ws; bias = bs; n0 = (xb - 24) * 128; mode = 3; }

    const int wm = (w >> 1) * 64, wn = (w & 1) * 64;

    f32x4 acc[4][4];
    for (int i = 0; i < 4; i++) for (int j = 0; j < 4; j++) acc[i][j] = (f32x4){0.f, 0.f, 0.f, 0.f};

    for (int k0 = 0; k0 < 1024; k0 += 64) {
        __syncthreads();
        for (int c = 0; c < 4; ++c) {
            int r = w * 32 + c * 8;
            async_load16(&X[(size_t)(m0 + r + lrow) * 1024 + k0 + gchunk], &As[r * 64]);
            async_load16(&W[(size_t)(n0 + r + lrow) * 1024 + k0 + gchunk], &Bs[r * 64]);
        }
        __syncthreads();
        for (int kk = 0; kk < 64; kk += 32) {
            const int csw = quad + (kk >> 3);
            bf16x8 a[4], b[4];
            for (int i = 0; i < 4; i++)
                a[i] = *(const bf16x8*)&As[(wm + i * 16 + l15) * 64 + ((csw ^ (l15 & 7)) * 8)];
            for (int j = 0; j < 4; j++)
                b[j] = *(const bf16x8*)&Bs[(wn + j * 16 + l15) * 64 + ((csw ^ (l15 & 7)) * 8)];
            for (int i = 0; i < 4; i++)
                for (int j = 0; j < 4; j++)
                    acc[i][j] = __builtin_amdgcn_mfma_f32_16x16x32_bf16(a[i], b[j], acc[i][j], 0, 0, 0);
        }
    }

    const float QSCALE = 0.125f * 1.44269504f;

    if (mode == 3) {
        for (int i = 0; i < 4; i++)
            for (int j = 0; j < 4; j++) {
                int gn = n0 + wn + j * 16 + l15;
                float bv_ = bias[gn];
                for (int r = 0; r < 4; r++) {
                    int gm = m0 + wm + i * 16 + quad * 4 + r;
                    float v = acc[i][j][r] + bv_;
                    float sg = __builtin_amdgcn_rcpf(1.0f + __builtin_amdgcn_exp2f(-v * 1.44269504f));
                    sb[(size_t)gm * 256 + gn] = sg * 0.1f + 0.95f;
                }
            }
        return;
    }

    __syncthreads();

    if (mode == 2) {
        for (int i = 0; i < 4; i++)
            for (int j = 0; j < 4; j++) {
                int gnl = wn + j * 16 + l15;
                float bv_ = bias[n0 + gnl];
                ushort4 pk;
                pk.x = f2bf(acc[i][j][0] + bv_);
                pk.y = f2bf(acc[i][j][1] + bv_);
                pk.z = f2bf(acc[i][j][2] + bv_);
                pk.w = f2bf(acc[i][j][3] + bv_);
                *(ushort4*)&Sm[gnl * 136 + wm + i * 16 + quad * 4] = pk;
            }
        __syncthreads();
        const int bb = m0 >> 11, sloc = m0 & 2047;
        for (int it = 0; it < 8; ++it) {
            int d = (tid >> 4) + it * 16;
            int s8 = (tid & 15) * 8;
            float4 v = *(float4*)&Sm[d * 136 + s8];
            int h = (n0 + d) >> 6, dd = d & 63;
            *(float4*)&VtG[(size_t)(bb * 16 + h) * 131072 + (size_t)dd * 2048 + sloc + s8] = v;
        }
    } else {
        for (int i = 0; i < 4; i++)
            for (int j = 0; j < 4; j++) {
                int gnl = wn + j * 16 + l15;
                float bv_ = bias[n0 + gnl];
                for (int r = 0; r < 4; r++) {
                    float v = acc[i][j][r] + bv_;
                    if (mode == 1) v *= QSCALE;
                    Sm[(wm + i * 16 + quad * 4 + r) * 136 + gnl] = f2bf(v);
                }
            }
        __syncthreads();
        ushort* dst = (mode == 1) ? Qb : Kb;
        for (int it = 0; it < 8; ++it) {
            int row = (tid >> 4) + it * 16, c = (tid & 15) * 8;
            *(float4*)&dst[(size_t)(m0 + row) * 1024 + n0 + c] = *(float4*)&Sm[row * 136 + c];
        }
    }
}

// Flash attention v21: v20 (K16-PV, 58.7us verified) + mt=2: each wave owns 32 q-rows,
// BQ=128/block, grid 512. LDS read law: reads/CU = waves/CU x steps x tile; halving
// waves/CU (16->8) at double per-wave output halves the 74%-busy LDS pipe's read
// traffic (65K->33K cy/CU). v11 showed 2 waves/SIMD is latency-risky, but v20's chain
// (QK->exp->pack->PV direct, no Ps round-trip) is much shorter than v11's.
// kb/vb loaded ONCE per step, shared across both mt groups. LDS 48KB (Qs gets its own
// 16KB region, alias trick removed). launch_bounds(256,2) -> 256-VGPR budget, no spill
// (v17's lesson). Pre-registered: attn >= 60us falsifies -> revert to v20.
__launch_bounds__(256, 2)
__global__ void attn_kernel(const ushort* __restrict__ Q, const ushort* __restrict__ K,
                            const ushort* __restrict__ Vt, const float* __restrict__ sb,
                            float* __restrict__ out)
{
    __shared__ __align__(16) ushort SmA[4 * 4096 + 8192];   // 48KB: Ks0|Ks1|Vs0|Vs1|Qs
    ushort* Ks0 = SmA;
    ushort* Ks1 = SmA + 4096;
    ushort* Vs0 = SmA + 8192;
    ushort* Vs1 = SmA + 12288;
    ushort* Qs  = SmA + 16384;   // 128 rows x 64, dedicated (no alias)

    const int tid = threadIdx.x, w = tid >> 6, lane = tid & 63;
    const int l15 = lane & 15, quad = lane >> 4;
    const int lrow = lane >> 3;
    const int gchunk = ((lane & 7) ^ lrow) * 8;

    // XCD swizzle: same bh (same K/V) -> same XCD
    const int wid = blockIdx.x;                  // 0..511
    const int r8 = wid & 7, jj = wid >> 3;       // jj 0..63
    const int bh = (jj & 3) * 8 + r8;            // 0..31
    const int qx = jj >> 2;                      // 0..15
    const int b = bh >> 4, h = bh & 15;
    const int q0 = qx * 128;
    const size_t rowbase = (size_t)b * 2048;
    const int cbase = h * 64;

    // global staging bases (per-thread, loop-invariant); each wave stages 16 rows
    const ushort* kg = K + (rowbase + w * 16 + lrow) * 1024 + cbase + gchunk;
    const ushort* vg = Vt + (size_t)bh * 131072 + (size_t)(w * 16 + lrow) * 2048 + gchunk;

    // prefetch K/V tile 0 FIRST
    for (int c = 0; c < 2; ++c) {
        async_load16(kg + c * 8192,  Ks0 + w * 1024 + c * 512);
        async_load16(vg + c * 16384, Vs0 + w * 1024 + c * 512);
    }

    // stage Q tile (128 rows) into Qs (pitch 64, XOR chunk swizzle), applying scale s
    for (int it = 0; it < 4; ++it) {
        int l = tid + it * 256;           // 0..1023
        int r = l >> 3, ch = l & 7;       // row 0..127, chunk 0..7
        int c = ch * 8;
        union { float4 f; ushort u[8]; } uu, oo;
        uu.f = *(const float4*)&Q[(rowbase + q0 + r) * 1024 + cbase + c];
        const float* sp = &sb[(rowbase + q0 + r) * 256 + ((cbase + c) >> 2)];
        float s0 = sp[0], s1 = sp[1];
        for (int j = 0; j < 4; j++) oo.u[j] = f2bf(bf2f(uu.u[j]) * s0);
        for (int j = 4; j < 8; j++) oo.u[j] = f2bf(bf2f(uu.u[j]) * s1);
        *(float4*)&Qs[r * 64 + ((ch ^ (r & 7)) * 8)] = oo.f;
    }
    __syncthreads();   // Qs writes visible to all waves

    // hoist loop-invariant Q frags; wave owns rows w*32 + mt*16 + l15
    bf16x8 aq[2][2];  // [mt][kk2]
    for (int mt = 0; mt < 2; mt++)
        for (int kk2 = 0; kk2 < 2; kk2++)
            aq[mt][kk2] = *(const bf16x8*)&Qs[(w * 32 + mt * 16 + l15) * 64
                                              + (((kk2 * 4 + quad) ^ (l15 & 7)) * 8)];

    // precomputed loop-invariant LDS offsets
    int kvoff[2][4];   // K frags (A-32 layout)
    for (int kk2 = 0; kk2 < 2; kk2++)
        for (int nt = 0; nt < 4; nt++)
            kvoff[kk2][nt] = (nt * 16 + l15) * 64 + (((quad + kk2 * 4) ^ (l15 & 7)) * 8);
    // V frags (B-16 layout): row d = nt*16+l15, keys kt2*16+quad*4+{0..3}
    int vaddr[4];
    for (int kt2 = 0; kt2 < 4; kt2++)
        vaddr[kt2] = l15 * 64 + (quad & 1) * 4
                   + (((kt2 * 2 + (quad >> 1)) ^ (l15 & 7)) * 8);

    // all-ones bf16 B-frag (K=16): osum = P @ 1 gives per-q-row softmax denominators
    const bf16x4 vones4 = {0x3F80, 0x3F80, 0x3F80, 0x3F80};

    f32x4 osum[2];
    f32x4 o[2][4];
    for (int mt = 0; mt < 2; mt++) {
        osum[mt] = (f32x4){0.f, 0.f, 0.f, 0.f};
        for (int nt = 0; nt < 4; nt++) o[mt][nt] = (f32x4){0.f, 0.f, 0.f, 0.f};
    }
    const f32x4 z4 = (f32x4){0.f, 0.f, 0.f, 0.f};

#define ATTN_STEP(KC, VC, KN, VN, KT, PREFETCH)                                                         \
    {                                                                                                   \
        __syncthreads(); /* vmcnt+lgkm drained: tile KT resident; buffers KN/VN free */                 \
        if (PREFETCH) {                                                                                 \
            const int nk = (KT) + 1;                                                                    \
            for (int c = 0; c < 2; ++c) {                                                               \
                async_load16(kg + nk * 65536 + c * 8192, KN + w * 1024 + c * 512);                      \
                async_load16(vg + nk * 64 + c * 16384,   VN + w * 1024 + c * 512);                      \
            }                                                                                           \
        }                                                                                               \
        bf16x8 kb[2][4];                                                                                \
        for (int kk2 = 0; kk2 < 2; kk2++)                                                               \
            for (int nt = 0; nt < 4; nt++)                                                              \
                kb[kk2][nt] = *(const bf16x8*)&KC[kvoff[kk2][nt]];                                      \
        bf16x4 vb4[4][4];                                                                               \
        _Pragma("unroll")                                                                               \
        for (int kt2 = 0; kt2 < 4; kt2++)                                                               \
            _Pragma("unroll")                                                                           \
            for (int nt = 0; nt < 4; nt++)                                                              \
                vb4[kt2][nt] = *(const bf16x4*)&VC[vaddr[kt2] + nt * 1024];                             \
        _Pragma("unroll")                                                                               \
        for (int mt = 0; mt < 2; mt++) {                                                                \
            /* S^T: A = K frag (m=key), B = Q frag (n=q-row) */                                         \
            f32x4 st[4];                                                                                \
            _Pragma("unroll")                                                                           \
            for (int kt2 = 0; kt2 < 4; kt2++) {                                                         \
                st[kt2] = __builtin_amdgcn_mfma_f32_16x16x32_bf16(kb[0][kt2], aq[mt][0], z4, 0, 0, 0);  \
                st[kt2] = __builtin_amdgcn_mfma_f32_16x16x32_bf16(kb[1][kt2], aq[mt][1], st[kt2],       \
                                                                  0, 0, 0);                             \
            }                                                                                           \
            /* exp + pack: du0=(r0,r1), du1=(r2,r3) -> directly the K=16 A-frag dwords */               \
            unsigned du0[4], du1[4];                                                                    \
            _Pragma("unroll")                                                                           \
            for (int kt2 = 0; kt2 < 4; kt2++) {                                                         \
                float p0 = __builtin_amdgcn_exp2f(st[kt2][0]);                                          \
                float p1 = __builtin_amdgcn_exp2f(st[kt2][1]);                                          \
                float p2 = __builtin_amdgcn_exp2f(st[kt2][2]);                                          \
                float p3 = __builtin_amdgcn_exp2f(st[kt2][3]);                                          \
                du0[kt2] = __builtin_amdgcn_perm(__builtin_bit_cast(unsigned, p1) + 0x8000u,            \
                                                 __builtin_bit_cast(unsigned, p0) + 0x8000u,            \
                                                 0x07060302u);                                          \
                du1[kt2] = __builtin_amdgcn_perm(__builtin_bit_cast(unsigned, p3) + 0x8000u,            \
                                                 __builtin_bit_cast(unsigned, p2) + 0x8000u,            \
                                                 0x07060302u);                                          \
            }                                                                                           \
            /* O += P @ V via K=16 MFMA: A-frag = held C-layout, zero data movement */                  \
            _Pragma("unroll")                                                                           \
            for (int kt2 = 0; kt2 < 4; kt2++) {                                                         \
                union { unsigned u[2]; bf16x4 v; } af;                                                  \
                af.u[0] = du0[kt2]; af.u[1] = du1[kt2];                                                 \
                osum[mt] = mfma16(af.v, vones4, osum[mt]);                                              \
                _Pragma("unroll")                                                                       \
                for (int nt = 0; nt < 4; nt++)                                                          \
                    o[mt][nt] = mfma16(af.v, vb4[kt2][nt], o[mt][nt]);                                  \
            }                                                                                           \
        }                                                                                               \
    }

    for (int kt = 0; kt < 32; kt += 2) {
        ATTN_STEP(Ks0, Vs0, Ks1, Vs1, kt, 1);
        ATTN_STEP(Ks1, Vs1, Ks0, Vs0, kt + 1, (kt + 2 < 32));
    }
#undef ATTN_STEP

    // finalize: osum[mt][r] is the full row sum for q-row quad*4+r (replicated over l15)
    for (int mt = 0; mt < 2; mt++) {
        for (int r = 0; r < 4; r++) {
            float iv = __builtin_amdgcn_rcpf(osum[mt][r]);
            int q = q0 + w * 32 + mt * 16 + quad * 4 + r;
            size_t base = (rowbase + q) * 1024 + cbase;
            for (int nt = 0; nt < 4; nt++)
                out[base + nt * 16 + l15] = o[mt][nt][r] * iv;
        }
    }
}

extern "C" void kernel_launch(void* const* d_in, const int* in_sizes, int n_in,
                              void* d_out, int out_size, void* d_ws, size_t ws_size,
                              hipStream_t stream) {
    const float* hs = (const float*)d_in[0];
    const float* Wq = (const float*)d_in[1];
    const float* bq = (const float*)d_in[2];
    const float* Wk = (const float*)d_in[3];
    const float* bk = (const float*)d_in[4];
    const float* Wv = (const float*)d_in[5];
    const float* bv = (const float*)d_in[6];
    const float* Ws = (const float*)d_in[7];
    const float* bs = (const float*)d_in[8];
    float* outp = (float*)d_out;

    char* ws = (char*)d_ws;
    ushort* Qb    = (ushort*)(ws);                 //  8 MB
    ushort* Kb    = (ushort*)(ws + 8388608);       //  8 MB
    ushort* VtG   = (ushort*)(ws + 16777216);      //  8 MB (V transposed [bh][d][s])
    float*  sb    = (float* )(ws + 25165824);      //  4 MB
    ushort* hs_bf = (ushort*)(ws + 29360128);      //  8 MB
    ushort* Wq_bf = (ushort*)(ws + 37748736);      //  2 MB
    ushort* Wk_bf = (ushort*)(ws + 39845888);      //  2 MB
    ushort* Wv_bf = (ushort*)(ws + 41943040);      //  2 MB
    ushort* Ws_bf = (ushort*)(ws + 44040192);      // 0.5 MB -> total 44,564,480 B

    cast_all<<<dim3(3712), dim3(256), 0, stream>>>(hs, Wq, Wk, Wv, Ws,
                                                   hs_bf, Wq_bf, Wk_bf, Wv_bf, Ws_bf);
    fused_qkvs<<<dim3(832), dim3(256), 0, stream>>>(hs_bf, Wq_bf, Wk_bf, Wv_bf, Ws_bf,
                                                    bq, bk, bv, bs, Qb, Kb, VtG, sb);
    attn_kernel<<<dim3(512), dim3(256), 0, stream>>>(Qb, Kb, VtG, sb, outp);
}